// Round 6
// baseline (682.592 us; speedup 1.0000x reference)
//
#include <hip/hip_runtime.h>

#define NN 2
#define CC 32
#define NCC 4
#define DD 96
#define WW 96
#define HH 96
#define PP (DD*WW*HH)          // 884736
#define NCP (NN*NCC*PP)        // 7077888
#define SD (WW*HH)             // 9216
#define SW HH                  // 96
#define DCH (PP/2048)          // 432 pooldots chunks per n
#define PB  (PP/1024)          // 864 attn blocks per n
#define DPW 352                // dotp row width: 288 dots + 8 waves * 8 sums
#define EPS 1e-5f
#define BIGF 1e30f

__device__ __forceinline__ float wave_reduce(float v) {
#pragma unroll
    for (int off = 32; off > 0; off >>= 1) v += __shfl_down(v, off, 64);
    return v;
}

__device__ __forceinline__ float sigf(float v) { return 1.f / (1.f + __expf(-v)); }

__device__ __forceinline__ void max2(float2& x, const float* p) {
    float2 a = *(const float2*)p;
    x.x = fmaxf(x.x, a.x); x.y = fmaxf(x.y, a.y);
}

__device__ __forceinline__ void min2(float2& x, const float* p) {
    float2 a = *(const float2*)p;
    x.x = fminf(x.x, a.x); x.y = fminf(x.y, a.y);
}

// ---- K1: fused sigmoid + 1-D max pool along H. Writes mask + maxH only. ----
__global__ __launch_bounds__(256) void k_poolH(const float* __restrict__ x,
                                               float* __restrict__ mask,
                                               float* __restrict__ omax) {
    int i = (blockIdx.x * 256 + threadIdx.x) * 4;
    int h0 = i % HH;                       // multiple of 4
    float4 xv = *(const float4*)(x + i);
    float v0 = sigf(xv.x), v1 = sigf(xv.y), v2 = sigf(xv.z), v3 = sigf(xv.w);
    float aM = -BIGF, bM = -BIGF, cM = -BIGF, dM = -BIGF;
    if (h0 > 0)  { aM = sigf(x[i-2]); bM = sigf(x[i-1]); }
    if (h0 < 92) { cM = sigf(x[i+4]); dM = sigf(x[i+5]); }
    float4 mo = make_float4(v0, v1, v2, v3), mx;
    mx.x = fmaxf(fmaxf(aM, bM), fmaxf(fmaxf(v0, v1), v2));
    mx.y = fmaxf(bM, fmaxf(fmaxf(v0, v1), fmaxf(v2, v3)));
    mx.z = fmaxf(fmaxf(fmaxf(v0, v1), fmaxf(v2, v3)), cM);
    mx.w = fmaxf(fmaxf(v1, v2), fmaxf(v3, fmaxf(cM, dM)));
    *(float4*)(mask + i) = mo;
    *(float4*)(omax + i) = mx;
}

// ---- K2: fused pools + dots, 2x1024-p halves reusing 32 KB LDS.
//      512 thr / 8 waves per 2048-p chunk. Per half: thread pools 2 p
//      (ero -> sE[0], dil -> sE[1], stored immediately, no reg carry);
//      barrier; dot phase (wave wv owns c = wv*4..+3, acc[4][9] persists
//      across halves); barrier. ONE cross-lane reduce at block end. ----
__global__ __launch_bounds__(512, 1) void k_pooldots(const float* __restrict__ t0,
                                                     const float* __restrict__ mask,
                                                     const float* __restrict__ feat,
                                                     float* __restrict__ dotp) {
    __shared__ __align__(16) float sE[2][NCC][1024];   // 32 KB: [0]=ero, [1]=dil
    int b = blockIdx.x;
    int n = b / DCH;
    int base = (b % DCH) * 2048;
    int t = threadIdx.x;
    int wv = t >> 6, ln = t & 63;

    float es_l[NCC], ds_l[NCC];
    float acc[4][9];
#pragma unroll
    for (int k = 0; k < NCC; ++k) { es_l[k] = 0.f; ds_l[k] = 0.f; }
#pragma unroll
    for (int cl = 0; cl < 4; ++cl)
#pragma unroll
        for (int q = 0; q < 9; ++q) acc[cl][q] = 0.f;

    const float* fp0 = feat + (size_t)(n*CC)*PP + base;

    for (int hh = 0; hh < 2; ++hh) {
        int pl = t * 2;                    // 0..1022, local within half
        int pt = base + hh*1024 + pl;      // intra-n p index
        int d  = pt / SD;
        int w  = (pt / SW) % WW;
        int h0 = pt % HH;                  // even

#pragma unroll
        for (int k = 0; k < NCC; ++k) {
            const size_t off = ((size_t)(n*NCC + k))*PP + pt;
            // dil = max over (dd,ww) in [-2,2]^2 of maxH
            float2 mx = make_float2(-BIGF, -BIGF);
#pragma unroll
            for (int dd = -2; dd <= 2; ++dd) {
                if ((unsigned)(d + dd) < DD) {
#pragma unroll
                    for (int ww = -2; ww <= 2; ++ww) {
                        if ((unsigned)(w + ww) < WW)
                            max2(mx, t0 + off + dd*SD + ww*SW);
                    }
                }
            }
            // ero = min(minH, minW, minD) of mask
            float2 m0 = *(const float2*)(mask + off);
            float l0 = BIGF, l1 = BIGF, r0 = BIGF, r1 = BIGF;
            if (h0 > 0)  { l0 = mask[off-2]; l1 = mask[off-1]; }
            if (h0 < 94) { r0 = mask[off+2]; r1 = mask[off+3]; }
            float2 mn;
            mn.x = fminf(fminf(l0, l1), fminf(m0.x, fminf(m0.y, r0)));
            mn.y = fminf(fminf(l1, m0.x), fminf(m0.y, fminf(r0, r1)));
            if (w >= 2)     min2(mn, mask + off - 2*SW);
            if (w >= 1)     min2(mn, mask + off -   SW);
            if (w + 1 < WW) min2(mn, mask + off +   SW);
            if (w + 2 < WW) min2(mn, mask + off + 2*SW);
            if (d >= 2)     min2(mn, mask + off - 2*SD);
            if (d >= 1)     min2(mn, mask + off -   SD);
            if (d + 1 < DD) min2(mn, mask + off +   SD);
            if (d + 2 < DD) min2(mn, mask + off + 2*SD);

            *(float2*)&sE[0][k][pl] = mn;   // store immediately, no reg carry
            *(float2*)&sE[1][k][pl] = mx;
            es_l[k] += mn.x + mn.y;
            ds_l[k] += mx.x + mx.y;
        }
        __syncthreads();

        // --- dot phase for this half: e-dots, d-dots, fsum together ---
#pragma unroll
        for (int it = 0; it < 4; ++it) {
            int po = it*256 + ln*4;
            float4 e4[NCC], d4[NCC];
#pragma unroll
            for (int k = 0; k < NCC; ++k) {
                e4[k] = *(const float4*)&sE[0][k][po];
                d4[k] = *(const float4*)&sE[1][k][po];
            }
#pragma unroll
            for (int cl = 0; cl < 4; ++cl) {
                float4 fv = *(const float4*)(fp0 + (size_t)(wv*4 + cl)*PP + hh*1024 + po);
#pragma unroll
                for (int k = 0; k < NCC; ++k) {
                    acc[cl][k]     += fv.x*e4[k].x + fv.y*e4[k].y + fv.z*e4[k].z + fv.w*e4[k].w;
                    acc[cl][4 + k] += fv.x*d4[k].x + fv.y*d4[k].y + fv.z*d4[k].z + fv.w*d4[k].w;
                }
                acc[cl][8] += fv.x + fv.y + fv.z + fv.w;
            }
        }
        __syncthreads();                   // protect sE reuse by next half
    }

    // --- e/d per-wave sums -> wave slots ---
#pragma unroll
    for (int k = 0; k < NCC; ++k) { es_l[k] = wave_reduce(es_l[k]); ds_l[k] = wave_reduce(ds_l[k]); }
    if (ln == 0) {
#pragma unroll
        for (int k = 0; k < NCC; ++k) {
            dotp[(size_t)b*DPW + 288 + wv*8 + k]     = es_l[k];
            dotp[(size_t)b*DPW + 288 + wv*8 + 4 + k] = ds_l[k];
        }
    }
    // --- one end-of-block reduce; each c owned by one wave, no atomics ---
#pragma unroll
    for (int cl = 0; cl < 4; ++cl) {
        int c = wv*4 + cl;
#pragma unroll
        for (int q = 0; q < 9; ++q) {
            float r = wave_reduce(acc[cl][q]);
            if (ln == 0) dotp[(size_t)b*DPW + c*9 + q] = r;
        }
    }
}

// ---- K3: stage-1 reduce of partials: 432 chunks -> 27 groups of 16. ----
__global__ __launch_bounds__(384) void k_dotred1(const float* __restrict__ dotp,
                                                 float* __restrict__ dotp2) {
    int t = threadIdx.x;
    if (t >= DPW) return;
    int g = blockIdx.x;            // [0, NN*27)
    int n = g / 27, gg = g % 27;
    const float* p = dotp + (size_t)(n*DCH + gg*16)*DPW + t;
    float s = 0.f;
#pragma unroll
    for (int j = 0; j < 16; ++j) s += p[(size_t)j*DPW];
    dotp2[(size_t)g*DPW + t] = s;
}

// ---- K4: stage-2 reduce + cluster. grid = NN. ----
__global__ __launch_bounds__(384) void k_dotred2c(const float* __restrict__ dotp2,
                                                  float* __restrict__ cluster) {
    __shared__ float vals[DPW];
    int t = threadIdx.x;
    int n = blockIdx.x;
    if (t < DPW) {
        float s = 0.f;
#pragma unroll
        for (int g = 0; g < 27; ++g) s += dotp2[((size_t)n*27 + g)*DPW + t];
        vals[t] = s;
    }
    __syncthreads();
    if (t < NCC*CC) {
        int k = t >> 5, c = t & 31;
        float es = 0.f, dsm = 0.f;
#pragma unroll
        for (int wv = 0; wv < 8; ++wv) {
            es  += vals[288 + wv*8 + k];
            dsm += vals[288 + wv*8 + 4 + k];
        }
        float de = vals[c*9 + k];
        float dd = vals[c*9 + 4 + k];
        float fs = vals[c*9 + 8];
        float esd = es + EPS;
        float dsd = dsm + EPS;
        float bsd = (float)PP - dsm + EPS;
        cluster[((n*NCC + k)*CC + c)*2 + 0] = de/esd + dd/dsd;
        cluster[((n*NCC + k)*CC + c)*2 + 1] = (fs - dd)/bsd;
    }
}

// ---- K5: attention BN-stats pass (unchanged). ----
__global__ __launch_bounds__(256) void k_attn_stats(const float* __restrict__ feat,
                                                    const float* __restrict__ cluster,
                                                    const float* __restrict__ kptr,
                                                    float* __restrict__ bnpart) {
    __shared__ float cl[NCC*CC*2];        // 256
    __shared__ float sacc[CC*2];
    int b = blockIdx.x;
    int n = b / PB;
    int p0 = (b % PB) * 1024 + (threadIdx.x << 2);
    cl[threadIdx.x] = cluster[n*(NCC*CC*2) + threadIdx.x];
    if (threadIdx.x < CC*2) sacc[threadIdx.x] = 0.f;
    __syncthreads();

    const float* fb = feat + (size_t)n*CC*PP + p0;

    float4 s0[NCC], s1[NCC];
#pragma unroll
    for (int k = 0; k < NCC; ++k) {
        s0[k] = make_float4(0.f, 0.f, 0.f, 0.f);
        s1[k] = make_float4(0.f, 0.f, 0.f, 0.f);
    }
#pragma unroll 8
    for (int c = 0; c < CC; ++c) {
        float4 fv = *(const float4*)(fb + (size_t)c*PP);
#pragma unroll
        for (int k = 0; k < NCC; ++k) {
            float2 cc2 = *(const float2*)&cl[(k*CC + c)*2];
            s0[k].x += fv.x*cc2.x; s0[k].y += fv.y*cc2.x;
            s0[k].z += fv.z*cc2.x; s0[k].w += fv.w*cc2.x;
            s1[k].x += fv.x*cc2.y; s1[k].y += fv.y*cc2.y;
            s1[k].z += fv.z*cc2.y; s1[k].w += fv.w*cc2.y;
        }
    }
    float4 w0[NCC], w1[NCC];
#pragma unroll
    for (int k = 0; k < NCC; ++k) {
        w0[k].x = 1.f/(1.f + __expf(s1[k].x - s0[k].x));
        w0[k].y = 1.f/(1.f + __expf(s1[k].y - s0[k].y));
        w0[k].z = 1.f/(1.f + __expf(s1[k].z - s0[k].z));
        w0[k].w = 1.f/(1.f + __expf(s1[k].w - s0[k].w));
        w1[k].x = 1.f - w0[k].x; w1[k].y = 1.f - w0[k].y;
        w1[k].z = 1.f - w0[k].z; w1[k].w = 1.f - w0[k].w;
    }

    float kk = kptr[0];
    int ln = threadIdx.x & 63;
#pragma unroll 8
    for (int c = 0; c < CC; ++c) {
        float4 fv = *(const float4*)(fb + (size_t)c*PP);   // L2-hit re-read
        float4 a = make_float4(0.f, 0.f, 0.f, 0.f);
#pragma unroll
        for (int k = 0; k < NCC; ++k) {
            float2 cc2 = *(const float2*)&cl[(k*CC + c)*2];
            a.x += w0[k].x*cc2.x + w1[k].x*cc2.y;
            a.y += w0[k].y*cc2.x + w1[k].y*cc2.y;
            a.z += w0[k].z*cc2.x + w1[k].z*cc2.y;
            a.w += w0[k].w*cc2.x + w1[k].w*cc2.y;
        }
        float4 o;
        o.x = 5.f*fv.x + kk*a.x; o.y = 5.f*fv.y + kk*a.y;
        o.z = 5.f*fv.z + kk*a.z; o.w = 5.f*fv.w + kk*a.w;
        float ls = o.x + o.y + o.z + o.w;
        float lq = o.x*o.x + o.y*o.y + o.z*o.z + o.w*o.w;
        ls = wave_reduce(ls);
        lq = wave_reduce(lq);
        if (ln == 0) { atomicAdd(&sacc[2*c], ls); atomicAdd(&sacc[2*c + 1], lq); }
    }
    __syncthreads();
    if (threadIdx.x < CC*2) bnpart[(size_t)b*(CC*2) + threadIdx.x] = sacc[threadIdx.x];
}

// ---- K6: reduce BN partials -> scale/shift. grid = CC blocks. ----
__global__ __launch_bounds__(256) void k_bnred(const float* __restrict__ bnpart,
                                               const float* __restrict__ wgt,
                                               const float* __restrict__ bias,
                                               float* __restrict__ scale,
                                               float* __restrict__ shift) {
    int c = blockIdx.x;
    float s = 0.f, q = 0.f;
    for (int b = threadIdx.x; b < NN*PB; b += 256) {
        s += bnpart[(size_t)b*(CC*2) + c*2];
        q += bnpart[(size_t)b*(CC*2) + c*2 + 1];
    }
    s = wave_reduce(s); q = wave_reduce(q);
    __shared__ float a[4], bb[4];
    if ((threadIdx.x & 63) == 0) { a[threadIdx.x >> 6] = s; bb[threadIdx.x >> 6] = q; }
    __syncthreads();
    if (threadIdx.x == 0) {
        float ts = a[0]+a[1]+a[2]+a[3];
        float tq = bb[0]+bb[1]+bb[2]+bb[3];
        float inv_n = 1.f / (float)((size_t)NN * PP);
        float mean = ts * inv_n;
        float var  = tq * inv_n - mean*mean;
        float inv  = 1.f / sqrtf(var + EPS);
        float sc = wgt[c] * inv;
        scale[c] = sc;
        shift[c] = bias[c] - mean*sc;
    }
}

// ---- K7: attention apply pass (unchanged). ----
__global__ __launch_bounds__(256) void k_attn_apply(const float* __restrict__ feat,
                                                    const float* __restrict__ cluster,
                                                    const float* __restrict__ kptr,
                                                    const float* __restrict__ scale,
                                                    const float* __restrict__ shift,
                                                    float* __restrict__ out) {
    __shared__ float cl[NCC*CC*2];
    __shared__ float ssc[CC], ssh[CC];
    int b = blockIdx.x;
    int n = b / PB;
    int p0 = (b % PB) * 1024 + (threadIdx.x << 2);
    cl[threadIdx.x] = cluster[n*(NCC*CC*2) + threadIdx.x];
    if (threadIdx.x < CC) {
        ssc[threadIdx.x] = scale[threadIdx.x];
        ssh[threadIdx.x] = shift[threadIdx.x];
    }
    __syncthreads();

    const float* fb = feat + (size_t)n*CC*PP + p0;

    float4 s0[NCC], s1[NCC];
#pragma unroll
    for (int k = 0; k < NCC; ++k) {
        s0[k] = make_float4(0.f, 0.f, 0.f, 0.f);
        s1[k] = make_float4(0.f, 0.f, 0.f, 0.f);
    }
#pragma unroll 8
    for (int c = 0; c < CC; ++c) {
        float4 fv = *(const float4*)(fb + (size_t)c*PP);
#pragma unroll
        for (int k = 0; k < NCC; ++k) {
            float2 cc2 = *(const float2*)&cl[(k*CC + c)*2];
            s0[k].x += fv.x*cc2.x; s0[k].y += fv.y*cc2.x;
            s0[k].z += fv.z*cc2.x; s0[k].w += fv.w*cc2.x;
            s1[k].x += fv.x*cc2.y; s1[k].y += fv.y*cc2.y;
            s1[k].z += fv.z*cc2.y; s1[k].w += fv.w*cc2.y;
        }
    }
    float4 w0[NCC], w1[NCC];
#pragma unroll
    for (int k = 0; k < NCC; ++k) {
        w0[k].x = 1.f/(1.f + __expf(s1[k].x - s0[k].x));
        w0[k].y = 1.f/(1.f + __expf(s1[k].y - s0[k].y));
        w0[k].z = 1.f/(1.f + __expf(s1[k].z - s0[k].z));
        w0[k].w = 1.f/(1.f + __expf(s1[k].w - s0[k].w));
        w1[k].x = 1.f - w0[k].x; w1[k].y = 1.f - w0[k].y;
        w1[k].z = 1.f - w0[k].z; w1[k].w = 1.f - w0[k].w;
    }

    float kk = kptr[0];
    float* ob = out + (size_t)n*CC*PP + p0;
#pragma unroll 8
    for (int c = 0; c < CC; ++c) {
        float4 fv = *(const float4*)(fb + (size_t)c*PP);
        float4 a = make_float4(0.f, 0.f, 0.f, 0.f);
#pragma unroll
        for (int k = 0; k < NCC; ++k) {
            float2 cc2 = *(const float2*)&cl[(k*CC + c)*2];
            a.x += w0[k].x*cc2.x + w1[k].x*cc2.y;
            a.y += w0[k].y*cc2.x + w1[k].y*cc2.y;
            a.z += w0[k].z*cc2.x + w1[k].z*cc2.y;
            a.w += w0[k].w*cc2.x + w1[k].w*cc2.y;
        }
        float sc = ssc[c], sh = ssh[c];
        float4 o;
        o.x = (5.f*fv.x + kk*a.x)*sc + sh;
        o.y = (5.f*fv.y + kk*a.y)*sc + sh;
        o.z = (5.f*fv.z + kk*a.z)*sc + sh;
        o.w = (5.f*fv.w + kk*a.w)*sc + sh;
        *(float4*)(ob + (size_t)c*PP) = o;
    }
}

extern "C" void kernel_launch(void* const* d_in, const int* in_sizes, int n_in,
                              void* d_out, int out_size, void* d_ws, size_t ws_size,
                              hipStream_t stream) {
    const float* feat = (const float*)d_in[0];
    const float* x    = (const float*)d_in[1];
    const float* kp   = (const float*)d_in[2];
    const float* bnw  = (const float*)d_in[3];
    const float* bnb  = (const float*)d_in[4];
    float* out = (float*)d_out;
    float* ws  = (float*)d_ws;

    float* mask    = ws;                         // NCP
    float* t0      = ws + 1*(size_t)NCP;         // NCP (maxH)
    float* scratch = ws + 2*(size_t)NCP;         // dot partials
    float* bnpart  = ws + 3*(size_t)NCP;         // 1728*64
    float* acc     = ws + 4*(size_t)NCP;
    float* dotp    = scratch;                    // 864*352 = 304128
    float* dotp2   = scratch + 320000;           // 54*352  = 19008
    float* cluster = acc;                        // 512
    float* scale   = acc + 512;                  // 32
    float* shift   = acc + 544;                  // 32

    k_poolH     <<<NCP/1024, 256, 0, stream>>>(x, mask, t0);
    k_pooldots  <<<NN*DCH, 512, 0, stream>>>(t0, mask, feat, dotp);
    k_dotred1   <<<NN*27, 384, 0, stream>>>(dotp, dotp2);
    k_dotred2c  <<<NN, 384, 0, stream>>>(dotp2, cluster);
    k_attn_stats<<<NN*PB, 256, 0, stream>>>(feat, cluster, kp, bnpart);
    k_bnred     <<<CC, 256, 0, stream>>>(bnpart, bnw, bnb, scale, shift);
    k_attn_apply<<<NN*PB, 256, 0, stream>>>(feat, cluster, kp, scale, shift, out);
}

// Round 7
// 373.020 us; speedup vs baseline: 1.8299x; 1.8299x over previous
//
#include <hip/hip_runtime.h>

#define NN 2
#define CC 32
#define NCC 4
#define DD 96
#define WW 96
#define HH 96
#define PP (DD*WW*HH)          // 884736
#define NCP (NN*NCC*PP)        // 7077888
#define SD (WW*HH)             // 9216
#define SW HH                  // 96
#define DCH (PP/2048)          // 432 pooldots chunks per n
#define PB  (PP/1024)          // 864 attn blocks per n
#define EPS 1e-5f
#define BIGF 1e30f

__device__ __forceinline__ float wave_reduce(float v) {
#pragma unroll
    for (int off = 32; off > 0; off >>= 1) v += __shfl_down(v, off, 64);
    return v;
}

__device__ __forceinline__ float dot8(float4 a0, float4 a1, float4 b0, float4 b1) {
    return a0.x*b0.x + a0.y*b0.y + a0.z*b0.z + a0.w*b0.w
         + a1.x*b1.x + a1.y*b1.y + a1.z*b1.z + a1.w*b1.w;
}

__device__ __forceinline__ float sigf(float v) { return 1.f / (1.f + __expf(-v)); }

__device__ __forceinline__ void max8(float4& x0, float4& x1, const float* p) {
    float4 a = *(const float4*)p, b = *(const float4*)(p + 4);
    x0.x = fmaxf(x0.x, a.x); x0.y = fmaxf(x0.y, a.y);
    x0.z = fmaxf(x0.z, a.z); x0.w = fmaxf(x0.w, a.w);
    x1.x = fmaxf(x1.x, b.x); x1.y = fmaxf(x1.y, b.y);
    x1.z = fmaxf(x1.z, b.z); x1.w = fmaxf(x1.w, b.w);
}

__device__ __forceinline__ void min8(float4& x0, float4& x1, const float* p) {
    float4 a = *(const float4*)p, b = *(const float4*)(p + 4);
    x0.x = fminf(x0.x, a.x); x0.y = fminf(x0.y, a.y);
    x0.z = fminf(x0.z, a.z); x0.w = fminf(x0.w, a.w);
    x1.x = fminf(x1.x, b.x); x1.y = fminf(x1.y, b.y);
    x1.z = fminf(x1.z, b.z); x1.w = fminf(x1.w, b.w);
}

// ---- K1: fused sigmoid + 1-D max pool along H. Writes mask + maxH only. ----
__global__ __launch_bounds__(256) void k_poolH(const float* __restrict__ x,
                                               float* __restrict__ mask,
                                               float* __restrict__ omax) {
    int i = (blockIdx.x * 256 + threadIdx.x) * 4;
    int h0 = i % HH;                       // multiple of 4
    float4 xv = *(const float4*)(x + i);
    float v0 = sigf(xv.x), v1 = sigf(xv.y), v2 = sigf(xv.z), v3 = sigf(xv.w);
    float aM = -BIGF, bM = -BIGF, cM = -BIGF, dM = -BIGF;
    if (h0 > 0)  { aM = sigf(x[i-2]); bM = sigf(x[i-1]); }
    if (h0 < 92) { cM = sigf(x[i+4]); dM = sigf(x[i+5]); }
    float4 mo = make_float4(v0, v1, v2, v3), mx;
    mx.x = fmaxf(fmaxf(aM, bM), fmaxf(fmaxf(v0, v1), v2));
    mx.y = fmaxf(bM, fmaxf(fmaxf(v0, v1), fmaxf(v2, v3)));
    mx.z = fmaxf(fmaxf(fmaxf(v0, v1), fmaxf(v2, v3)), cM);
    mx.w = fmaxf(fmaxf(v1, v2), fmaxf(v3, fmaxf(cM, dM)));
    *(float4*)(mask + i) = mo;
    *(float4*)(omax + i) = mx;
}

// ---- K2: fused W-pool + D-pool + erode/dilate + e/d sums + feat dots.
//      R3 structure (256 thr, 8 p/thread, e/dv in regs) + two edits:
//      (1) depth-1 feat prefetch in the c-loop; (2) wave-private sacc
//      slots (plain ds_write by lane 0) instead of contended LDS atomics. ----
__global__ __launch_bounds__(256, 2) void k_pooldots(const float* __restrict__ t0,
                                                     const float* __restrict__ mask,
                                                     const float* __restrict__ feat,
                                                     float* __restrict__ dotp) {
    int b = blockIdx.x;
    int n = b / DCH;
    int pt = (b % DCH) * 2048 + threadIdx.x * 8;   // intra-n offset; 8 | 96 so
    int d  = pt / SD;                              // thread's 8 p share one row
    int w  = (pt / SW) % WW;
    int h0 = pt % HH;                              // in {0,8,...,88}
    int wv = threadIdx.x >> 6, ln = threadIdx.x & 63;

    __shared__ float sacc[4][296];                 // per-wave slots: no atomics

    float4 e[NCC][2], dv[NCC][2];
#pragma unroll
    for (int k = 0; k < NCC; ++k) {
        const size_t off = (size_t)(n*NCC + k)*PP + pt;
        // dil = max over (dd,ww) in [-2,2]^2 of maxH  (== maxD(maxW(maxH)))
        float4 mx0 = make_float4(-BIGF,-BIGF,-BIGF,-BIGF), mx1 = mx0;
#pragma unroll
        for (int dd = -2; dd <= 2; ++dd) {
            if ((unsigned)(d + dd) < DD) {
#pragma unroll
                for (int ww = -2; ww <= 2; ++ww) {
                    if ((unsigned)(w + ww) < WW)
                        max8(mx0, mx1, t0 + off + dd*SD + ww*SW);
                }
            }
        }
        // ero = min(minH, minW, minD) of mask
        float4 m0 = *(const float4*)(mask + off);
        float4 m1 = *(const float4*)(mask + off + 4);
        float l0 = BIGF, l1 = BIGF, r0 = BIGF, r1 = BIGF;
        if (h0 > 0)  { l0 = mask[off-2]; l1 = mask[off-1]; }
        if (h0 < 88) { r0 = mask[off+8]; r1 = mask[off+9]; }
        float mv0=l0, mv1=l1, mv2=m0.x, mv3=m0.y, mv4=m0.z, mv5=m0.w,
              mv6=m1.x, mv7=m1.y, mv8=m1.z, mv9=m1.w, mv10=r0, mv11=r1;
        float4 mn0, mn1;   // minH per element (window j-2..j+2)
        mn0.x = fminf(fminf(mv0,mv1), fminf(mv2, fminf(mv3,mv4)));
        mn0.y = fminf(fminf(mv1,mv2), fminf(mv3, fminf(mv4,mv5)));
        mn0.z = fminf(fminf(mv2,mv3), fminf(mv4, fminf(mv5,mv6)));
        mn0.w = fminf(fminf(mv3,mv4), fminf(mv5, fminf(mv6,mv7)));
        mn1.x = fminf(fminf(mv4,mv5), fminf(mv6, fminf(mv7,mv8)));
        mn1.y = fminf(fminf(mv5,mv6), fminf(mv7, fminf(mv8,mv9)));
        mn1.z = fminf(fminf(mv6,mv7), fminf(mv8, fminf(mv9,mv10)));
        mn1.w = fminf(fminf(mv7,mv8), fminf(mv9, fminf(mv10,mv11)));
        // minW taps
        if (w >= 2)     min8(mn0, mn1, mask + off - 2*SW);
        if (w >= 1)     min8(mn0, mn1, mask + off -   SW);
        if (w + 1 < WW) min8(mn0, mn1, mask + off +   SW);
        if (w + 2 < WW) min8(mn0, mn1, mask + off + 2*SW);
        // minD taps
        if (d >= 2)     min8(mn0, mn1, mask + off - 2*SD);
        if (d >= 1)     min8(mn0, mn1, mask + off -   SD);
        if (d + 1 < DD) min8(mn0, mn1, mask + off +   SD);
        if (d + 2 < DD) min8(mn0, mn1, mask + off + 2*SD);

        e[k][0] = mn0; e[k][1] = mn1;
        dv[k][0] = mx0; dv[k][1] = mx1;
        float th_e = mn0.x+mn0.y+mn0.z+mn0.w + mn1.x+mn1.y+mn1.z+mn1.w;
        float th_d = mx0.x+mx0.y+mx0.z+mx0.w + mx1.x+mx1.y+mx1.z+mx1.w;
        th_e = wave_reduce(th_e);
        th_d = wave_reduce(th_d);
        if (ln == 0) {
            sacc[wv][288 + k] = th_e;
            sacc[wv][292 + k] = th_d;
        }
    }

    // feat dots (single feat pass shared across all 4 k), depth-1 prefetch
    const float* pf = feat + (size_t)(n*CC)*PP + pt;
    float4 fa = *(const float4*)pf;
    float4 fb = *(const float4*)(pf + 4);
    for (int c = 0; c < CC; ++c) {
        // issue next c's load BEFORE the reduce chain of this c
        int cn = (c + 1 < CC) ? (c + 1) : c;
        const float* pn = pf + (size_t)cn*PP;
        float4 na = *(const float4*)pn;
        float4 nb = *(const float4*)(pn + 4);
        float vals[9];
#pragma unroll
        for (int k = 0; k < NCC; ++k) {
            vals[k]     = dot8(fa, fb, e[k][0],  e[k][1]);
            vals[4 + k] = dot8(fa, fb, dv[k][0], dv[k][1]);
        }
        vals[8] = fa.x+fa.y+fa.z+fa.w + fb.x+fb.y+fb.z+fb.w;
#pragma unroll
        for (int q = 0; q < 9; ++q) {
            float r = wave_reduce(vals[q]);
            if (ln == 0) sacc[wv][c*9 + q] = r;    // plain write, no RMW
        }
        fa = na; fb = nb;
    }
    __syncthreads();
    for (int t = threadIdx.x; t < 296; t += 256)
        dotp[(size_t)b*296 + t] = sacc[0][t] + sacc[1][t] + sacc[2][t] + sacc[3][t];
}

// ---- K3: stage-1 reduce of partials: 432 chunks -> 27 groups of 16. ----
__global__ __launch_bounds__(320) void k_dotred1(const float* __restrict__ dotp,
                                                 float* __restrict__ dotp2) {
    int t = threadIdx.x;
    if (t >= 296) return;
    int g = blockIdx.x;            // [0, NN*27)
    int n = g / 27, gg = g % 27;
    const float* p = dotp + (size_t)(n*DCH + gg*16)*296 + t;
    float s = 0.f;
#pragma unroll
    for (int j = 0; j < 16; ++j) s += p[(size_t)j*296];
    dotp2[(size_t)g*296 + t] = s;
}

// ---- K4: stage-2 reduce + cluster. grid = NN. ----
__global__ __launch_bounds__(320) void k_dotred2c(const float* __restrict__ dotp2,
                                                  float* __restrict__ cluster) {
    __shared__ float vals[296];
    int t = threadIdx.x;
    int n = blockIdx.x;
    if (t < 296) {
        float s = 0.f;
#pragma unroll
        for (int g = 0; g < 27; ++g) s += dotp2[((size_t)n*27 + g)*296 + t];
        vals[t] = s;
    }
    __syncthreads();
    if (t < NCC*CC) {
        int k = t >> 5, c = t & 31;
        float de = vals[c*9 + k];
        float dd = vals[c*9 + 4 + k];
        float fs = vals[c*9 + 8];
        float es = vals[288 + k] + EPS;
        float ds = vals[292 + k] + EPS;
        float bs = (float)PP - vals[292 + k] + EPS;
        cluster[((n*NCC + k)*CC + c)*2 + 0] = de/es + dd/ds;
        cluster[((n*NCC + k)*CC + c)*2 + 1] = (fs - dd)/bs;
    }
}

// ---- K5: attention BN-stats pass (unchanged from R3). ----
__global__ __launch_bounds__(256) void k_attn_stats(const float* __restrict__ feat,
                                                    const float* __restrict__ cluster,
                                                    const float* __restrict__ kptr,
                                                    float* __restrict__ bnpart) {
    __shared__ float cl[NCC*CC*2];        // 256
    __shared__ float sacc[CC*2];
    int b = blockIdx.x;
    int n = b / PB;
    int p0 = (b % PB) * 1024 + (threadIdx.x << 2);
    cl[threadIdx.x] = cluster[n*(NCC*CC*2) + threadIdx.x];
    if (threadIdx.x < CC*2) sacc[threadIdx.x] = 0.f;
    __syncthreads();

    const float* fb = feat + (size_t)n*CC*PP + p0;

    float4 s0[NCC], s1[NCC];
#pragma unroll
    for (int k = 0; k < NCC; ++k) {
        s0[k] = make_float4(0.f, 0.f, 0.f, 0.f);
        s1[k] = make_float4(0.f, 0.f, 0.f, 0.f);
    }
#pragma unroll 8
    for (int c = 0; c < CC; ++c) {
        float4 fv = *(const float4*)(fb + (size_t)c*PP);
#pragma unroll
        for (int k = 0; k < NCC; ++k) {
            float2 cc2 = *(const float2*)&cl[(k*CC + c)*2];
            s0[k].x += fv.x*cc2.x; s0[k].y += fv.y*cc2.x;
            s0[k].z += fv.z*cc2.x; s0[k].w += fv.w*cc2.x;
            s1[k].x += fv.x*cc2.y; s1[k].y += fv.y*cc2.y;
            s1[k].z += fv.z*cc2.y; s1[k].w += fv.w*cc2.y;
        }
    }
    float4 w0[NCC], w1[NCC];
#pragma unroll
    for (int k = 0; k < NCC; ++k) {
        w0[k].x = 1.f/(1.f + __expf(s1[k].x - s0[k].x));
        w0[k].y = 1.f/(1.f + __expf(s1[k].y - s0[k].y));
        w0[k].z = 1.f/(1.f + __expf(s1[k].z - s0[k].z));
        w0[k].w = 1.f/(1.f + __expf(s1[k].w - s0[k].w));
        w1[k].x = 1.f - w0[k].x; w1[k].y = 1.f - w0[k].y;
        w1[k].z = 1.f - w0[k].z; w1[k].w = 1.f - w0[k].w;
    }

    float kk = kptr[0];
    int ln = threadIdx.x & 63;
#pragma unroll 8
    for (int c = 0; c < CC; ++c) {
        float4 fv = *(const float4*)(fb + (size_t)c*PP);   // L2-hit re-read
        float4 a = make_float4(0.f, 0.f, 0.f, 0.f);
#pragma unroll
        for (int k = 0; k < NCC; ++k) {
            float2 cc2 = *(const float2*)&cl[(k*CC + c)*2];
            a.x += w0[k].x*cc2.x + w1[k].x*cc2.y;
            a.y += w0[k].y*cc2.x + w1[k].y*cc2.y;
            a.z += w0[k].z*cc2.x + w1[k].z*cc2.y;
            a.w += w0[k].w*cc2.x + w1[k].w*cc2.y;
        }
        float4 o;
        o.x = 5.f*fv.x + kk*a.x; o.y = 5.f*fv.y + kk*a.y;
        o.z = 5.f*fv.z + kk*a.z; o.w = 5.f*fv.w + kk*a.w;
        float ls = o.x + o.y + o.z + o.w;
        float lq = o.x*o.x + o.y*o.y + o.z*o.z + o.w*o.w;
        ls = wave_reduce(ls);
        lq = wave_reduce(lq);
        if (ln == 0) { atomicAdd(&sacc[2*c], ls); atomicAdd(&sacc[2*c + 1], lq); }
    }
    __syncthreads();
    if (threadIdx.x < CC*2) bnpart[(size_t)b*(CC*2) + threadIdx.x] = sacc[threadIdx.x];
}

// ---- K6: reduce BN partials -> scale/shift. grid = CC blocks. ----
__global__ __launch_bounds__(256) void k_bnred(const float* __restrict__ bnpart,
                                               const float* __restrict__ wgt,
                                               const float* __restrict__ bias,
                                               float* __restrict__ scale,
                                               float* __restrict__ shift) {
    int c = blockIdx.x;
    float s = 0.f, q = 0.f;
    for (int b = threadIdx.x; b < NN*PB; b += 256) {
        s += bnpart[(size_t)b*(CC*2) + c*2];
        q += bnpart[(size_t)b*(CC*2) + c*2 + 1];
    }
    s = wave_reduce(s); q = wave_reduce(q);
    __shared__ float a[4], bb[4];
    if ((threadIdx.x & 63) == 0) { a[threadIdx.x >> 6] = s; bb[threadIdx.x >> 6] = q; }
    __syncthreads();
    if (threadIdx.x == 0) {
        float ts = a[0]+a[1]+a[2]+a[3];
        float tq = bb[0]+bb[1]+bb[2]+bb[3];
        float inv_n = 1.f / (float)((size_t)NN * PP);
        float mean = ts * inv_n;
        float var  = tq * inv_n - mean*mean;
        float inv  = 1.f / sqrtf(var + EPS);
        float sc = wgt[c] * inv;
        scale[c] = sc;
        shift[c] = bias[c] - mean*sc;
    }
}

// ---- K7: attention apply pass (unchanged from R3). ----
__global__ __launch_bounds__(256) void k_attn_apply(const float* __restrict__ feat,
                                                    const float* __restrict__ cluster,
                                                    const float* __restrict__ kptr,
                                                    const float* __restrict__ scale,
                                                    const float* __restrict__ shift,
                                                    float* __restrict__ out) {
    __shared__ float cl[NCC*CC*2];
    __shared__ float ssc[CC], ssh[CC];
    int b = blockIdx.x;
    int n = b / PB;
    int p0 = (b % PB) * 1024 + (threadIdx.x << 2);
    cl[threadIdx.x] = cluster[n*(NCC*CC*2) + threadIdx.x];
    if (threadIdx.x < CC) {
        ssc[threadIdx.x] = scale[threadIdx.x];
        ssh[threadIdx.x] = shift[threadIdx.x];
    }
    __syncthreads();

    const float* fb = feat + (size_t)n*CC*PP + p0;

    float4 s0[NCC], s1[NCC];
#pragma unroll
    for (int k = 0; k < NCC; ++k) {
        s0[k] = make_float4(0.f, 0.f, 0.f, 0.f);
        s1[k] = make_float4(0.f, 0.f, 0.f, 0.f);
    }
#pragma unroll 8
    for (int c = 0; c < CC; ++c) {
        float4 fv = *(const float4*)(fb + (size_t)c*PP);
#pragma unroll
        for (int k = 0; k < NCC; ++k) {
            float2 cc2 = *(const float2*)&cl[(k*CC + c)*2];
            s0[k].x += fv.x*cc2.x; s0[k].y += fv.y*cc2.x;
            s0[k].z += fv.z*cc2.x; s0[k].w += fv.w*cc2.x;
            s1[k].x += fv.x*cc2.y; s1[k].y += fv.y*cc2.y;
            s1[k].z += fv.z*cc2.y; s1[k].w += fv.w*cc2.y;
        }
    }
    float4 w0[NCC], w1[NCC];
#pragma unroll
    for (int k = 0; k < NCC; ++k) {
        w0[k].x = 1.f/(1.f + __expf(s1[k].x - s0[k].x));
        w0[k].y = 1.f/(1.f + __expf(s1[k].y - s0[k].y));
        w0[k].z = 1.f/(1.f + __expf(s1[k].z - s0[k].z));
        w0[k].w = 1.f/(1.f + __expf(s1[k].w - s0[k].w));
        w1[k].x = 1.f - w0[k].x; w1[k].y = 1.f - w0[k].y;
        w1[k].z = 1.f - w0[k].z; w1[k].w = 1.f - w0[k].w;
    }

    float kk = kptr[0];
    float* ob = out + (size_t)n*CC*PP + p0;
#pragma unroll 8
    for (int c = 0; c < CC; ++c) {
        float4 fv = *(const float4*)(fb + (size_t)c*PP);
        float4 a = make_float4(0.f, 0.f, 0.f, 0.f);
#pragma unroll
        for (int k = 0; k < NCC; ++k) {
            float2 cc2 = *(const float2*)&cl[(k*CC + c)*2];
            a.x += w0[k].x*cc2.x + w1[k].x*cc2.y;
            a.y += w0[k].y*cc2.x + w1[k].y*cc2.y;
            a.z += w0[k].z*cc2.x + w1[k].z*cc2.y;
            a.w += w0[k].w*cc2.x + w1[k].w*cc2.y;
        }
        float sc = ssc[c], sh = ssh[c];
        float4 o;
        o.x = (5.f*fv.x + kk*a.x)*sc + sh;
        o.y = (5.f*fv.y + kk*a.y)*sc + sh;
        o.z = (5.f*fv.z + kk*a.z)*sc + sh;
        o.w = (5.f*fv.w + kk*a.w)*sc + sh;
        *(float4*)(ob + (size_t)c*PP) = o;
    }
}

extern "C" void kernel_launch(void* const* d_in, const int* in_sizes, int n_in,
                              void* d_out, int out_size, void* d_ws, size_t ws_size,
                              hipStream_t stream) {
    const float* feat = (const float*)d_in[0];
    const float* x    = (const float*)d_in[1];
    const float* kp   = (const float*)d_in[2];
    const float* bnw  = (const float*)d_in[3];
    const float* bnb  = (const float*)d_in[4];
    float* out = (float*)d_out;
    float* ws  = (float*)d_ws;

    float* mask    = ws;                         // NCP
    float* t0      = ws + 1*(size_t)NCP;         // NCP (maxH)
    float* scratch = ws + 2*(size_t)NCP;         // dot partials
    float* bnpart  = ws + 3*(size_t)NCP;         // 1728*64
    float* acc     = ws + 4*(size_t)NCP;
    float* dotp    = scratch;                    // 864*296 = 255744
    float* dotp2   = scratch + 262144;           // 54*296  = 15984
    float* cluster = acc;                        // 512
    float* scale   = acc + 512;                  // 32
    float* shift   = acc + 544;                  // 32

    k_poolH     <<<NCP/1024, 256, 0, stream>>>(x, mask, t0);
    k_pooldots  <<<NN*DCH, 256, 0, stream>>>(t0, mask, feat, dotp);
    k_dotred1   <<<NN*27, 320, 0, stream>>>(dotp, dotp2);
    k_dotred2c  <<<NN, 320, 0, stream>>>(dotp2, cluster);
    k_attn_stats<<<NN*PB, 256, 0, stream>>>(feat, cluster, kp, bnpart);
    k_bnred     <<<CC, 256, 0, stream>>>(bnpart, bnw, bnb, scale, shift);
    k_attn_apply<<<NN*PB, 256, 0, stream>>>(feat, cluster, kp, scale, shift, out);
}